// Round 7
// baseline (993.469 us; speedup 1.0000x reference)
//
#include <hip/hip_runtime.h>

typedef unsigned short u16;
typedef __attribute__((ext_vector_type(8))) short bf16x8;
typedef __attribute__((ext_vector_type(4))) float f32x4;
typedef __attribute__((ext_vector_type(4))) unsigned short u16x4;

#define MFMA16(a, b, c) __builtin_amdgcn_mfma_f32_16x16x32_bf16((a), (b), (c), 0, 0, 0)

#define SEQ 4096
#define SCALE 0.07216878364870323f   // (192)^-0.5
#define LOGTHETA 9.210340371976184f  // ln(10000)

__device__ __forceinline__ u16 f2bf(float f) {
  union { float f; unsigned u; } c; c.f = f;
  unsigned u = c.u;
  unsigned r = (u + 0x7fffu + ((u >> 16) & 1u)) >> 16;  // RNE
  return (u16)r;
}
__device__ __forceinline__ float bf2f(u16 b) {
  union { unsigned u; float f; } c; c.u = ((unsigned)b) << 16;
  return c.f;
}

// ---------------- fp32 -> bf16 conversion (vectorized) ----------------
__global__ void cvt_bf16(const float* __restrict__ src, u16* __restrict__ dst, int n4) {
  int stride = gridDim.x * blockDim.x;
  for (int i = blockIdx.x * blockDim.x + threadIdx.x; i < n4; i += stride) {
    f32x4 v = ((const f32x4*)src)[i];
    u16x4 o;
    o[0] = f2bf(v[0]); o[1] = f2bf(v[1]); o[2] = f2bf(v[2]); o[3] = f2bf(v[3]);
    ((u16x4*)dst)[i] = o;
  }
}

// ---------------- transpose wkv_b nope block: wt[h][c][d] = w[h*256+d][c] ----------------
__global__ void trans_wkvb(const u16* __restrict__ w, u16* __restrict__ wt) {
  int stride = gridDim.x * blockDim.x;
  for (int i = blockIdx.x * blockDim.x + threadIdx.x; i < 16 * 512 * 128; i += stride) {
    int h = i >> 16;
    int r = i & 65535;
    int c = r >> 7, d = r & 127;
    wt[i] = w[(h * 256 + d) * 512 + c];
  }
}

// ---------------- transpose to 32-token panels: vt2[t>>5][c][t&31] = kva[t*576+c], c<512 ------
__global__ void trans_vt(const u16* __restrict__ kva, u16* __restrict__ vt2) {
  __shared__ u16 tile[64][65];
  int c0 = blockIdx.x * 64;
  int t0 = blockIdx.y * 64;
  for (int k = 0; k < 16; k++) {
    int el = threadIdx.x + k * 256;
    int r = el >> 6, c = el & 63;            // r = token off, c = chan off
    tile[r][c] = kva[(t0 + r) * 576 + c0 + c];
  }
  __syncthreads();
  for (int k = 0; k < 16; k++) {
    int el = threadIdx.x + k * 256;
    int r = el >> 6, c = el & 63;            // chan = c0+r, token = t0+c
    int t = t0 + c;
    vt2[(t >> 5) * 16384 + (c0 + r) * 32 + (t & 31)] = tile[c][r];
  }
}

// ---------------- RMSNorm q (in-place, 4096 x 1536 bf16) ----------------
__global__ void rms_q_kernel(u16* __restrict__ qa, const float* __restrict__ w) {
  int row = blockIdx.x;
  u16* p = qa + row * 1536;
  float vals[6];
  float ss = 0.f;
#pragma unroll
  for (int k = 0; k < 6; k++) {
    float v = bf2f(p[threadIdx.x + k * 256]);
    vals[k] = v;
    ss += v * v;
  }
  for (int m = 1; m < 64; m <<= 1) ss += __shfl_xor(ss, m);
  __shared__ float red[4];
  int wid = threadIdx.x >> 6;
  if ((threadIdx.x & 63) == 0) red[wid] = ss;
  __syncthreads();
  float tot = red[0] + red[1] + red[2] + red[3];
  float rr = rsqrtf(tot / 1536.f + 1e-6f);
#pragma unroll
  for (int k = 0; k < 6; k++) {
    int i = threadIdx.x + k * 256;
    p[i] = f2bf(vals[k] * rr * w[i]);
  }
}

// ---------------- RMSNorm kv (cols 0..511) + rope k_pe (cols 512..575), in-place ----------------
__global__ void rms_kv_kernel(u16* __restrict__ kva, const float* __restrict__ w) {
  int t = blockIdx.x;
  u16* p = kva + t * 576;
  float v0 = bf2f(p[threadIdx.x]);
  float v1 = bf2f(p[threadIdx.x + 256]);
  float ss = v0 * v0 + v1 * v1;
  for (int m = 1; m < 64; m <<= 1) ss += __shfl_xor(ss, m);
  __shared__ float red[4];
  int wid = threadIdx.x >> 6;
  if ((threadIdx.x & 63) == 0) red[wid] = ss;
  __syncthreads();
  float tot = red[0] + red[1] + red[2] + red[3];
  float rr = rsqrtf(tot / 512.f + 1e-6f);
  p[threadIdx.x] = f2bf(v0 * rr * w[threadIdx.x]);
  p[threadIdx.x + 256] = f2bf(v1 * rr * w[threadIdx.x + 256]);
  if (threadIdx.x < 32) {
    int i = threadIdx.x;
    float x0 = bf2f(p[512 + 2 * i]);
    float x1 = bf2f(p[512 + 2 * i + 1]);
    float invf = expf(-((float)(2 * i) / 64.f) * LOGTHETA);
    float ang = (float)t * invf;
    float cs = cosf(ang), sn = sinf(ang);
    p[512 + 2 * i] = f2bf(x0 * cs - x1 * sn);
    p[512 + 2 * i + 1] = f2bf(x0 * sn + x1 * cs);
  }
}

// ---------------- rope q_pe (pre-scaled by SCALE): qb -> qcat[..., 512:576] ----------------
__global__ void rope_q_kernel(const u16* __restrict__ qb, u16* __restrict__ qcat) {
  int stride = gridDim.x * blockDim.x;
  for (int idx = blockIdx.x * blockDim.x + threadIdx.x; idx < 4096 * 512; idx += stride) {
    int s = idx >> 9;
    int r = idx & 511;
    int h = r >> 5, i = r & 31;
    float x0 = bf2f(qb[s * 3072 + h * 192 + 128 + 2 * i]);
    float x1 = bf2f(qb[s * 3072 + h * 192 + 128 + 2 * i + 1]);
    float invf = expf(-((float)(2 * i) / 64.f) * LOGTHETA);
    float ang = (float)s * invf;
    float cs = cosf(ang) * SCALE, sn = sinf(ang) * SCALE;
    qcat[s * 9216 + h * 576 + 512 + 2 * i] = f2bf(x0 * cs - x1 * sn);
    qcat[s * 9216 + h * 576 + 512 + 2 * i + 1] = f2bf(x0 * sn + x1 * cs);
  }
}

// ---------------- tiled MFMA GEMM: C = oscale * A(M,K) @ W(N,K)^T ----------------
template <int BN, bool OUTF32>
__launch_bounds__(256)
__global__ void gemm_tiled(const u16* __restrict__ A, int lda, int az,
                           const u16* __restrict__ W, int ldw, int wz,
                           void* __restrict__ Cp, int ldc, int cz, int K, float oscale) {
  constexpr int NCH = 8 + BN / 16;       // chunks per K-step (A:8, B:BN/16)
  constexpr int NBF = BN / 32;           // B frags per wave
  __shared__ __align__(16) u16 lds[2][NCH * 512];

  int z = blockIdx.z;
  int wid = threadIdx.x >> 6, lane = threadIdx.x & 63;
  int quad = lane >> 4, l16 = lane & 15;
  int wr = wid >> 1, wc = wid & 1;       // wave 2x2 grid
  int m0 = blockIdx.y * 128;
  int n0 = blockIdx.x * BN;

  const u16* Az = A + (size_t)z * az;
  const u16* Wz = W + (size_t)z * wz;

  f32x4 acc[4][NBF];
#pragma unroll
  for (int i = 0; i < 4; i++)
#pragma unroll
    for (int j = 0; j < NBF; j++) acc[i][j] = {0.f, 0.f, 0.f, 0.f};

  // stage K-step 0 into buf 0
#pragma unroll
  for (int jj = 0; jj < NCH / 4; jj++) {
    int c = jj * 4 + wid;
    const u16* src = (c < 8) ? (Az + (m0 + c * 16 + l16) * (size_t)lda + quad * 8)
                             : (Wz + (n0 + (c - 8) * 16 + l16) * (size_t)ldw + quad * 8);
    __builtin_amdgcn_global_load_lds(
        (const __attribute__((address_space(1))) unsigned int*)src,
        (__attribute__((address_space(3))) unsigned int*)&lds[0][c * 512], 16, 0, 0);
  }

  int buf = 0;
  for (int k0 = 0; k0 < K; k0 += 32) {
    __syncthreads();
    if (k0 + 32 < K) {
      int k1 = k0 + 32;
#pragma unroll
      for (int jj = 0; jj < NCH / 4; jj++) {
        int c = jj * 4 + wid;
        const u16* src = (c < 8) ? (Az + (m0 + c * 16 + l16) * (size_t)lda + k1 + quad * 8)
                                 : (Wz + (n0 + (c - 8) * 16 + l16) * (size_t)ldw + k1 + quad * 8);
        __builtin_amdgcn_global_load_lds(
            (const __attribute__((address_space(1))) unsigned int*)src,
            (__attribute__((address_space(3))) unsigned int*)&lds[buf ^ 1][c * 512], 16, 0, 0);
      }
    }
    const u16* base = &lds[buf][0];
    bf16x8 a[4], b[NBF];
#pragma unroll
    for (int i = 0; i < 4; i++)
      a[i] = *(const bf16x8*)(base + (wr * 4 + i) * 512 + lane * 8);
#pragma unroll
    for (int j = 0; j < NBF; j++)
      b[j] = *(const bf16x8*)(base + (8 + wc * NBF + j) * 512 + lane * 8);
#pragma unroll
    for (int i = 0; i < 4; i++)
#pragma unroll
      for (int j = 0; j < NBF; j++) acc[i][j] = MFMA16(a[i], b[j], acc[i][j]);
    buf ^= 1;
  }

#pragma unroll
  for (int i = 0; i < 4; i++) {
    int row = m0 + wr * 64 + i * 16 + quad * 4;
#pragma unroll
    for (int j = 0; j < NBF; j++) {
      int col = n0 + wc * (BN / 2) + j * 16 + l16;
#pragma unroll
      for (int r = 0; r < 4; r++) {
        size_t cbase = (size_t)z * cz + (size_t)(row + r) * ldc + col;
        if (OUTF32) ((float*)Cp)[cbase] = acc[i][j][r] * oscale;
        else        ((u16*)Cp)[cbase] = f2bf(acc[i][j][r] * oscale);
      }
    }
  }
}

// ---------------- flash attention v6 ----------------
// Block = (head h, 128 q-rows), 8 waves; 1 block/CU (~145 KB LDS).
// QK phase: wave wid owns rows m0 = qb0+wid*16 (Q pinned in VGPRs, pre-scaled).
// P (=exp(s), no max-subtraction) written to plds in A-operand fragment chunks:
//   chunk g = rows g*16..+15 x tokens 0..31; elem(r,t) at u16 ((t>>3)*16+r)*8+(t&7).
// PV phase: wave (rg=wid>>2, ch=wid&3) owns rows rg*64..+63 x cols ch*128..+127 ->
//   reads only 4 P chunks + 8 V chunks (8 KB) instead of full 32 KB V: PV LDS
//   traffic 256->96 KB/tile. Cross-wave P requires a second barrier per tile;
//   staging for ti+1 is issued before QK so its latency still hides under QK.
// li per-row sums shared via li_lds in the epilogue.
__launch_bounds__(512, 2)
__global__ void attn_kernel(const u16* __restrict__ qcat, const u16* __restrict__ kcat,
                            const u16* __restrict__ vt2, u16* __restrict__ ctx) {
  __shared__ __align__(16) u16 lds[2][34816];      // 2 x 68 KB: K 36*512 then V 32*512
  __shared__ __align__(16) u16 plds[8][512];       // 8 KB P chunks (A-operand layout)
  __shared__ float li_lds[128];

  int wid = threadIdx.x >> 6, lane = threadIdx.x & 63;
  int quad = lane >> 4, l16 = lane & 15;
  int bx = blockIdx.x;
  int h = bx & 15;
  int jb = 31 - (bx >> 4);       // heavy-first
  int qb0 = jb << 7;             // 128-row q block
  int m0 = qb0 + wid * 16;       // QK row base for this wave
  int rg = wid >> 2, ch = wid & 3;   // PV: rows rg*64..+63, cols ch*128..+127
  int pr0 = rg * 64;

  // Q fragments pinned in registers (already scaled by SCALE upstream)
  bf16x8 q[18];
  {
    const u16* qb = qcat + (m0 + l16) * 9216 + h * 576 + quad * 8;
#pragma unroll
    for (int kk = 0; kk < 18; kk++) q[kk] = *(const bf16x8*)(qb + kk * 32);
  }

  f32x4 zero = {0.f, 0.f, 0.f, 0.f};
  bf16x8 zero8 = {0, 0, 0, 0, 0, 0, 0, 0};
  f32x4 o[32];                   // o[i*8+j]: rows pr0+i*16+quad*4+r, col ch*128+j*16+l16
#pragma unroll
  for (int k = 0; k < 32; k++) o[k] = zero;
  float li[4] = {0.f, 0.f, 0.f, 0.f};

  int nt = (qb0 >> 5) + 4;

  // staging slots: chunk c = jj*8+wid; K chunks 0..35, V chunks 36..67
  const u16* sp[9];
  int sstr[9], soff[9];
  bool sact[9];
#pragma unroll
  for (int jj = 0; jj < 9; jj++) {
    int c = jj * 8 + wid;
    sact[jj] = (c < 68);
    soff[jj] = c * 512;
    if (c < 36) {
      int kk = c >> 1, half = c & 1;
      sp[jj] = kcat + (half * 16 + l16) * 576 + kk * 32 + quad * 8;
      sstr[jj] = 32 * 576;
    } else {
      int ct = c - 36;
      sp[jj] = vt2 + (ct * 16 + l16) * 32 + quad * 8;
      sstr[jj] = 16384;
    }
  }

  // prologue: stage tile 0 into buf 0
#pragma unroll
  for (int jj = 0; jj < 9; jj++) {
    if (sact[jj]) {
      __builtin_amdgcn_global_load_lds(
          (const __attribute__((address_space(1))) unsigned int*)sp[jj],
          (__attribute__((address_space(3))) unsigned int*)&lds[0][soff[jj]], 16, 0, 0);
      sp[jj] += sstr[jj];
    }
  }

  for (int ti = 0; ti < nt; ti++) {
    __syncthreads();   // barrier1: stage(ti) visible; buf^1 free; prev P reads done
    int buf = ti & 1;
    if (ti + 1 < nt) {
      u16* dbase = &lds[buf ^ 1][0];
#pragma unroll
      for (int jj = 0; jj < 9; jj++) {
        if (sact[jj]) {
          __builtin_amdgcn_global_load_lds(
              (const __attribute__((address_space(1))) unsigned int*)sp[jj],
              (__attribute__((address_space(3))) unsigned int*)&dbase[soff[jj]], 16, 0, 0);
          sp[jj] += sstr[jj];
        }
      }
    }

    int t0 = ti << 5;
    // ---- QK phase: rows m0..m0+15 ----
    if (t0 <= m0 + 15) {
      const u16* kb = &lds[buf][0];
      f32x4 s0 = zero, s1 = zero;
#pragma unroll
      for (int kk = 0; kk < 18; kk++) {
        bf16x8 b0 = *(const bf16x8*)(&kb[(kk * 2 + 0) * 512 + lane * 8]);
        bf16x8 b1 = *(const bf16x8*)(&kb[(kk * 2 + 1) * 512 + lane * 8]);
        s0 = MFMA16(q[kk], b0, s0);
        s1 = MFMA16(q[kk], b1, s1);
      }
      int tc0 = t0 + l16, tc1 = t0 + 16 + l16;
#pragma unroll
      for (int r = 0; r < 4; r++) {
        int mrow = m0 + quad * 4 + r;
        float e0 = (tc0 <= mrow) ? __expf(s0[r]) : 0.f;
        float e1 = (tc1 <= mrow) ? __expf(s1[r]) : 0.f;
        li[r] += e0 + e1;
        int row = quad * 4 + r;
        plds[wid][((l16 >> 3) * 16 + row) * 8 + (l16 & 7)] = f2bf(e0);
        plds[wid][((2 + (l16 >> 3)) * 16 + row) * 8 + (l16 & 7)] = f2bf(e1);
      }
    } else {
      *(bf16x8*)&plds[wid][lane * 8] = zero8;   // masked tile: zero own P chunk
    }
    __syncthreads();   // barrier2: P visible to all waves

    // ---- PV phase: rows pr0..pr0+63, cols ch*128..+127 ----
    if (t0 <= qb0 + pr0 + 63) {
      const u16* vb = &lds[buf][18432];
      bf16x8 a[4];
#pragma unroll
      for (int i = 0; i < 4; i++)
        a[i] = *(const bf16x8*)(&plds[rg * 4 + i][lane * 8]);
#pragma unroll
      for (int j = 0; j < 8; j++) {
        bf16x8 bv = *(const bf16x8*)(&vb[(ch * 8 + j) * 512 + lane * 8]);
#pragma unroll
        for (int i = 0; i < 4; i++) o[i * 8 + j] = MFMA16(a[i], bv, o[i * 8 + j]);
      }
    }
  }

  // epilogue: reduce li across token-lanes, publish per-row sums, normalize + store
#pragma unroll
  for (int r = 0; r < 4; r++) {
    float s = li[r];
    s += __shfl_xor(s, 1);
    s += __shfl_xor(s, 2);
    s += __shfl_xor(s, 4);
    s += __shfl_xor(s, 8);
    li[r] = s;
  }
  if (l16 == 0) {
#pragma unroll
    for (int r = 0; r < 4; r++) li_lds[wid * 16 + quad * 4 + r] = li[r];
  }
  __syncthreads();
#pragma unroll
  for (int i = 0; i < 4; i++) {
    int rowl = pr0 + i * 16 + quad * 4;
    f32x4 inv;
#pragma unroll
    for (int r = 0; r < 4; r++) inv[r] = 1.f / li_lds[rowl + r];
    int grow = qb0 + rowl;
#pragma unroll
    for (int j = 0; j < 8; j++) {
      int col = ch * 128 + j * 16 + l16;
      f32x4 val = o[i * 8 + j] * inv;
#pragma unroll
      for (int r = 0; r < 4; r++)
        ctx[(size_t)(grow + r) * 8192 + h * 512 + col] = f2bf(val[r]);
    }
  }
}

// ---------------- launch ----------------
extern "C" void kernel_launch(void* const* d_in, const int* in_sizes, int n_in,
                              void* d_out, int out_size, void* d_ws, size_t ws_size,
                              hipStream_t stream) {
  const float* x = (const float*)d_in[0];
  const float* wqa = (const float*)d_in[1];
  const float* qnw = (const float*)d_in[2];
  const float* wqb = (const float*)d_in[3];
  const float* wkva = (const float*)d_in[4];
  const float* kvnw = (const float*)d_in[5];
  const float* wkvb = (const float*)d_in[6];
  const float* wo = (const float*)d_in[7];

  u16* ws = (u16*)d_ws;
  u16* XB = ws;                        //  4096*2048
  u16* WQAB = ws + 8388608;            //  1536*2048
  u16* WQBB = ws + 11534336;           //  3072*1536
  u16* WKVAB = ws + 16252928;          //  576*2048
  u16* WKVBB = ws + 17432576;          //  4096*512
  u16* WKVBT = ws + 19529728;          //  16*512*128
  u16* WOB = ws + 20578304;            //  2048*2048
  u16* QA = ws + 24772608;             //  4096*1536
  u16* KVA = ws + 31064064;            //  4096*576
  u16* VT = ws + 33423360;             //  512*4096 (panel layout)
  u16* QCAT = ws + 35520512;           //  4096*16*576
  u16* CTX = ws + 73269248;            //  4096*16*512
  u16* QB = CTX;                       //  alias: dead before attn writes CTX
  u16* VBUF = QCAT;                    //  alias: qcat dead before v-GEMM writes

  dim3 blk(256);

  cvt_bf16<<<1024, blk, 0, stream>>>(x, XB, 2097152);
  cvt_bf16<<<1024, blk, 0, stream>>>(wqa, WQAB, 786432);
  cvt_bf16<<<1024, blk, 0, stream>>>(wqb, WQBB, 1179648);
  cvt_bf16<<<1024, blk, 0, stream>>>(wkva, WKVAB, 294912);
  cvt_bf16<<<1024, blk, 0, stream>>>(wkvb, WKVBB, 524288);
  cvt_bf16<<<1024, blk, 0, stream>>>(wo, WOB, 1048576);
  trans_wkvb<<<1024, blk, 0, stream>>>(WKVBB, WKVBT);

  // q_a = x @ wq_a^T ; kv_a = x @ wkv_a^T
  gemm_tiled<128, false><<<dim3(12, 32, 1), blk, 0, stream>>>(XB, 2048, 0, WQAB, 2048, 0, QA, 1536, 0, 2048, 1.f);
  gemm_tiled<64, false><<<dim3(9, 32, 1), blk, 0, stream>>>(XB, 2048, 0, WKVAB, 2048, 0, KVA, 576, 0, 2048, 1.f);

  rms_q_kernel<<<4096, blk, 0, stream>>>(QA, qnw);
  rms_kv_kernel<<<4096, blk, 0, stream>>>(KVA, kvnw);
  trans_vt<<<dim3(8, 64), blk, 0, stream>>>(KVA, VT);

  // q = qn @ wq_b^T
  gemm_tiled<128, false><<<dim3(24, 32, 1), blk, 0, stream>>>(QA, 1536, 0, WQBB, 1536, 0, QB, 3072, 0, 1536, 1.f);

  // q_abs per head -> qcat[..., :512], pre-scaled by SCALE
  gemm_tiled<128, false><<<dim3(4, 32, 16), blk, 0, stream>>>(QB, 3072, 192, WKVBT, 128, 65536, QCAT, 9216, 576, 128, SCALE);
  rope_q_kernel<<<2048, blk, 0, stream>>>(QB, QCAT);

  attn_kernel<<<512, dim3(512), 0, stream>>>(QCAT, KVA, VT, CTX);

  // v per head: ctx @ wkv_b[h,128:,:]^T
  gemm_tiled<128, false><<<dim3(1, 32, 16), blk, 0, stream>>>(CTX, 8192, 512, WKVBB + 65536, 512, 131072, VBUF, 2048, 128, 512, 1.f);

  // out = v @ wo^T (fp32 out)
  gemm_tiled<128, true><<<dim3(16, 32, 1), blk, 0, stream>>>(VBUF, 2048, 0, WOB, 2048, 0, d_out, 2048, 0, 2048, 1.f);
}